// Round 1
// baseline (1094.791 us; speedup 1.0000x reference)
//
#include <hip/hip_runtime.h>

// Problem: B=2, H=16, S=2048, D=64 attention, fp32 in/out.
// out = concat(attention [B,H,S,S], sum_value [B,H,S,D]) flat fp32.
// mask [B,1,1,S] bool -> int32; mask TRUE means score := -1e30 (masked out).

#define S_DIM 2048
#define D_DIM 64
#define QT 32              // q rows per block
#define KT 64              // k-tile size
#define EROW 2056          // e-tile row stride in bf16 elems (2048 + 8 pad)
#define KROW 72            // K/V tile row stride in bf16 elems (64 + 8 pad)
#define NTHREADS 512
#define NBH 32             // B*H
#define ATTN_ELEMS ((size_t)NBH * S_DIM * S_DIM)  // 134217728

typedef short s16x8 __attribute__((ext_vector_type(8)));
typedef float f32x4 __attribute__((ext_vector_type(4)));

__device__ __forceinline__ short f2bf(float x) {
  unsigned int b = __float_as_uint(x);
  b += 0x7FFF + ((b >> 16) & 1);        // round-to-nearest-even
  return (short)(b >> 16);
}
__device__ __forceinline__ float bf2f(short h) {
  return __uint_as_float(((unsigned int)(unsigned short)h) << 16);
}

extern "C" __global__ __launch_bounds__(NTHREADS)
void attn_kernel(const float* __restrict__ Q, const float* __restrict__ K,
                 const float* __restrict__ V, const int* __restrict__ Mask,
                 float* __restrict__ Out) {
  extern __shared__ char smem_raw[];
  unsigned short* e_tile = (unsigned short*)smem_raw;          // QT * EROW bf16
  unsigned short* kl = e_tile + (size_t)QT * EROW;             // KT * KROW bf16
  unsigned short* vt = kl + (size_t)KT * KROW;                 // D_DIM * KROW bf16 (V transposed)
  float* sums = (float*)(vt + (size_t)D_DIM * KROW);           // QT floats
  int* maskv = (int*)(sums + QT);                              // KT ints

  const int t = threadIdx.x;
  const int lane = t & 63;
  const int wave = t >> 6;        // 0..7
  const int l15 = lane & 15;
  const int quad = lane >> 4;     // 0..3
  const int tq = wave >> 2;       // 0..1 : q half (16 rows)
  const int tn = wave & 3;        // 0..3 : 16-col quarter

  const int blk = blockIdx.x;     // 2048 blocks
  const int qt_idx = blk & 63;    // 64 q-tiles per head
  const int bh = blk >> 6;        // 0..31
  const int b = bh >> 4;          // H = 16
  const int q0 = qt_idx * QT;

  const float* Qbase = Q + (size_t)bh * S_DIM * D_DIM;
  const float* Kbase = K + (size_t)bh * S_DIM * D_DIM;
  const float* Vbase = V + (size_t)bh * S_DIM * D_DIM;
  const int* mbase = Mask + b * S_DIM;
  float* attn_out = Out + (size_t)bh * S_DIM * S_DIM + (size_t)q0 * S_DIM;
  float* sv_out = Out + ATTN_ELEMS + ((size_t)bh * S_DIM + q0) * D_DIM;

  // --- Load Q fragments (A-operand layout): row = q0+tq*16+l15, k-chunk c:
  // d = c*32 + quad*8 + j. Scale by 1/sqrt(64)=0.125, convert to bf16.
  s16x8 qf[2];
  {
    const float* qrow = Qbase + (size_t)(q0 + tq * 16 + l15) * D_DIM;
#pragma unroll
    for (int c = 0; c < 2; ++c) {
      const int d0 = c * 32 + quad * 8;
#pragma unroll
      for (int j = 0; j < 8; ++j) qf[c][j] = f2bf(qrow[d0 + j] * 0.125f);
    }
  }

  f32x4 pv_acc = {0.f, 0.f, 0.f, 0.f};
  float sum_part = 0.f;
  const int sq = t >> 4;     // 0..31 : q row this thread sums
  const int sslot = t & 15;  // 16 col-groups of 4

  for (int kt = 0; kt < S_DIM / KT; ++kt) {
    const int kk0 = kt * KT;
    __syncthreads();  // protect kl/vt from overwrite while prev PV reads
    // --- Stage K tile (row-major bf16) and V tile (transposed bf16) ---
#pragma unroll
    for (int i = 0; i < 2; ++i) {
      const int f = t + i * NTHREADS;   // 0..1023
      const int row = f >> 4;           // local k row 0..63
      const int c4 = f & 15;            // float4 index within row
      const float4 kv = *(const float4*)(Kbase + (size_t)(kk0 + row) * D_DIM + c4 * 4);
      unsigned short* kd = kl + row * KROW + c4 * 4;
      kd[0] = f2bf(kv.x); kd[1] = f2bf(kv.y); kd[2] = f2bf(kv.z); kd[3] = f2bf(kv.w);
      const float4 vv = *(const float4*)(Vbase + (size_t)(kk0 + row) * D_DIM + c4 * 4);
      vt[(c4 * 4 + 0) * KROW + row] = f2bf(vv.x);
      vt[(c4 * 4 + 1) * KROW + row] = f2bf(vv.y);
      vt[(c4 * 4 + 2) * KROW + row] = f2bf(vv.z);
      vt[(c4 * 4 + 3) * KROW + row] = f2bf(vv.w);
    }
    if (t < KT) maskv[t] = mbase[kk0 + t];
    __syncthreads();

    // --- QK^T: wave computes 16x16 tile (rows tq*16.., cols tn*16..) ---
    f32x4 sc = {0.f, 0.f, 0.f, 0.f};
#pragma unroll
    for (int c = 0; c < 2; ++c) {
      const s16x8 bf = *(const s16x8*)(kl + (tn * 16 + l15) * KROW + c * 32 + quad * 8);
      sc = __builtin_amdgcn_mfma_f32_16x16x32_bf16(qf[c], bf, sc, 0, 0, 0);
    }
    // --- mask + exp, write e (bf16) into persistent e-tile ---
    {
      const int col = tn * 16 + l15;
      const int m = maskv[col];
#pragma unroll
      for (int r = 0; r < 4; ++r) {
        const int row = tq * 16 + quad * 4 + r;
        const float e = m ? 0.f : __expf(sc[r]);
        e_tile[row * EROW + kk0 + col] = f2bf(e);
      }
    }
    __syncthreads();  // e-tile section ready for PV + sums

    // --- row-sum partials from e-tile (bf16-consistent) ---
    {
      const unsigned short* sp = e_tile + sq * EROW + kk0 + sslot * 4;
      sum_part += bf2f(sp[0]) + bf2f(sp[1]) + bf2f(sp[2]) + bf2f(sp[3]);
    }
    // --- PV: wave computes 16x16 out tile (rows tq*16.., d-cols tn*16..) ---
#pragma unroll
    for (int c = 0; c < 2; ++c) {
      const s16x8 af = *(const s16x8*)(e_tile + (tq * 16 + l15) * EROW + kk0 + c * 32 + quad * 8);
      const s16x8 bf = *(const s16x8*)(vt + (tn * 16 + l15) * KROW + c * 32 + quad * 8);
      pv_acc = __builtin_amdgcn_mfma_f32_16x16x32_bf16(af, bf, pv_acc, 0, 0, 0);
    }
  }

  // --- Reduce row sums across the 16 lanes sharing q row `sq` ---
#pragma unroll
  for (int o = 8; o >= 1; o >>= 1) sum_part += __shfl_xor(sum_part, o);
  if (sslot == 0) sums[sq] = sum_part;
  __syncthreads();
  if (t < QT) { const float s = sums[t]; sums[t] = 1.f / fmaxf(s, 1e-30f); }
  __syncthreads();

  // --- Write sum_value (normalized PV accumulators) ---
  {
    const int col = tn * 16 + l15;
#pragma unroll
    for (int r = 0; r < 4; ++r) {
      const int row = tq * 16 + quad * 4 + r;
      sv_out[(size_t)row * D_DIM + col] = pv_acc[r] * sums[row];
    }
  }
  // --- Write normalized attention (coalesced float4) ---
#pragma unroll 4
  for (int i = 0; i < 32; ++i) {
    const int f = t + i * NTHREADS;   // 0..16383 float4 slots
    const int q = f >> 9;             // 512 float4 per row
    const int c4 = f & 511;
    const unsigned short* ep = e_tile + q * EROW + c4 * 4;
    const float inv = sums[q];
    float4 o;
    o.x = bf2f(ep[0]) * inv;
    o.y = bf2f(ep[1]) * inv;
    o.z = bf2f(ep[2]) * inv;
    o.w = bf2f(ep[3]) * inv;
    *(float4*)(attn_out + (size_t)q * S_DIM + c4 * 4) = o;
  }
}

extern "C" void kernel_launch(void* const* d_in, const int* in_sizes, int n_in,
                              void* d_out, int out_size, void* d_ws, size_t ws_size,
                              hipStream_t stream) {
  const float* Q = (const float*)d_in[0];
  const float* K = (const float*)d_in[1];
  const float* V = (const float*)d_in[2];
  const int* M = (const int*)d_in[3];
  float* out = (float*)d_out;

  const size_t lds_bytes =
      (size_t)QT * EROW * 2 + (size_t)KT * KROW * 2 + (size_t)D_DIM * KROW * 2 +
      QT * sizeof(float) + KT * sizeof(int);  // = 150400 B

  dim3 grid(NBH * (S_DIM / QT));  // 2048 blocks
  dim3 block(NTHREADS);
  hipLaunchKernelGGL(attn_kernel, grid, block, lds_bytes, stream, Q, K, V, M, out);
}

// Round 2
// 790.209 us; speedup vs baseline: 1.3854x; 1.3854x over previous
//
#include <hip/hip_runtime.h>
#include <stdint.h>

// B=2,H=16,S=2048,D=64 attention. out = concat(attn [2,16,2048,2048], sv [2,16,2048,64]) fp32.
// mask int32, TRUE => masked (score -1e30 => e=0).
// Strategy: prep kernel writes bf16 Q(scaled), K(swizzled tiles), V^T(swizzled tiles) to ws;
// main kernel: global_load_lds staging, MFMA QK^T + PV, e kept in 64 VGPRs, LDS-staged
// coalesced fp32 attention writes.

#define S_DIM 2048
#define D_DIM 64
#define QT 32
#define KTILE 64
#define NKT 32
#define NT 512
#define NBH 32
#define ETS 72
#define STS 68
#define ATTN_ELEMS ((size_t)NBH * S_DIM * S_DIM)
#define QELEMS ((size_t)NBH * S_DIM * D_DIM)   // 4194304 elems = 8 MB bf16

typedef short s16x8 __attribute__((ext_vector_type(8)));
typedef float f32x4 __attribute__((ext_vector_type(4)));

__device__ __forceinline__ unsigned short f2bf(float x) {
  unsigned int u = __float_as_uint(x);
  u += 0x7FFF + ((u >> 16) & 1);   // RNE
  return (unsigned short)(u >> 16);
}
__device__ __forceinline__ float bf2f(unsigned short h) {
  return __uint_as_float(((unsigned int)h) << 16);
}

__device__ __forceinline__ void glds16(const void* g, void* l) {
  __builtin_amdgcn_global_load_lds(
      (const __attribute__((address_space(1))) unsigned int*)g,
      (__attribute__((address_space(3))) unsigned int*)l, 16, 0, 0);
}

// ---------------- pre-pass: bf16 conversion + tiling/swizzle ----------------
// K tiles: per (bh,kt): elem (r,d) at r*64 + (d ^ ((r&7)*8))   [r=s&63]
// Vt tiles: per (bh,kt): elem (d,c) at d*64 + (c ^ ((d&7)*8))  [c=s&63], value V[s][d]
extern "C" __global__ __launch_bounds__(256)
void prep_kernel(const float* __restrict__ Q, const float* __restrict__ K,
                 const float* __restrict__ V, unsigned short* __restrict__ Qb,
                 unsigned short* __restrict__ Kb, unsigned short* __restrict__ Vtb) {
  __shared__ unsigned short vtl[64 * 65];
  const int t = threadIdx.x;
  const int blk = blockIdx.x;
  if (blk < 1024) {
    const int bh = blk >> 5;
    const int kt = blk & 31;
    const float* Ksrc = K + ((size_t)bh * S_DIM + kt * KTILE) * D_DIM;
    const float* Vsrc = V + ((size_t)bh * S_DIM + kt * KTILE) * D_DIM;
    unsigned short* Kdst = Kb + ((size_t)bh * S_DIM + kt * KTILE) * D_DIM;
    unsigned short* Vdst = Vtb + ((size_t)bh * S_DIM + kt * KTILE) * D_DIM;
#pragma unroll
    for (int i = 0; i < 2; ++i) {
      const int f = t + i * 256;
      const int row = f >> 3, db = f & 7;
      const float* s = Ksrc + row * 64 + db * 8;
      s16x8 v;
#pragma unroll
      for (int j = 0; j < 8; ++j) v[j] = (short)f2bf(s[j]);
      *(s16x8*)(Kdst + row * 64 + ((db * 8) ^ ((row & 7) * 8))) = v;
    }
#pragma unroll
    for (int i = 0; i < 4; ++i) {
      const int f = t + i * 256;
      const int row = f >> 4, c4 = f & 15;
      const float4 vv = *(const float4*)(Vsrc + row * 64 + c4 * 4);
      vtl[(c4 * 4 + 0) * 65 + row] = f2bf(vv.x);
      vtl[(c4 * 4 + 1) * 65 + row] = f2bf(vv.y);
      vtl[(c4 * 4 + 2) * 65 + row] = f2bf(vv.z);
      vtl[(c4 * 4 + 3) * 65 + row] = f2bf(vv.w);
    }
    __syncthreads();
#pragma unroll
    for (int i = 0; i < 2; ++i) {
      const int f = t + i * 256;
      const int d = f >> 3, b8 = f & 7;
      s16x8 v;
#pragma unroll
      for (int j = 0; j < 8; ++j) v[j] = (short)vtl[d * 65 + b8 * 8 + j];
      *(s16x8*)(Vdst + d * 64 + ((b8 * 8) ^ ((d & 7) * 8))) = v;
    }
  } else {
    const size_t base = (size_t)(blk - 1024) * 2048 + (size_t)t * 8;
    const float4 a = *(const float4*)(Q + base);
    const float4 b2 = *(const float4*)(Q + base + 4);
    s16x8 v;
    v[0] = (short)f2bf(a.x * 0.125f);  v[1] = (short)f2bf(a.y * 0.125f);
    v[2] = (short)f2bf(a.z * 0.125f);  v[3] = (short)f2bf(a.w * 0.125f);
    v[4] = (short)f2bf(b2.x * 0.125f); v[5] = (short)f2bf(b2.y * 0.125f);
    v[6] = (short)f2bf(b2.z * 0.125f); v[7] = (short)f2bf(b2.w * 0.125f);
    *(s16x8*)(Qb + base) = v;
  }
}

// ---------------- main kernel ----------------
extern "C" __global__ __launch_bounds__(NT, 4)
void attn_kernel(const int* __restrict__ Mask, const unsigned short* __restrict__ Qb,
                 const unsigned short* __restrict__ Kb, const unsigned short* __restrict__ Vtb,
                 float* __restrict__ Out) {
  __shared__ unsigned short bufK[2][KTILE * D_DIM];   // 16 KB
  __shared__ unsigned short bufV[2][KTILE * D_DIM];   // 16 KB
  __shared__ unsigned short et[QT * ETS];             // 4.5 KB
  __shared__ float stage[2][QT * STS];                // 17 KB
  __shared__ float sums_part[8 * 16];
  __shared__ float inv_sums[QT];

  const int t = threadIdx.x;
  const int lane = t & 63;
  const int wave = t >> 6;     // 0..7
  const int l15 = lane & 15;
  const int quad = lane >> 4;  // 0..3
  const int tq = wave >> 2;    // 0..1
  const int tn = wave & 3;     // 0..3

  const int blk = blockIdx.x;
  const int qt_idx = blk & 63;
  const int bh = blk >> 6;
  const int q0 = qt_idx * QT;

  const char* kbase = (const char*)(Kb + (size_t)bh * S_DIM * D_DIM);
  const char* vbase = (const char*)(Vtb + (size_t)bh * S_DIM * D_DIM);
  const int* mrow = Mask + (bh >> 4) * S_DIM + tn * 16 + l15;

  // Q A-fragments (row = q0+tq*16+l15, k = c*32+quad*8+j), pre-scaled bf16
  const unsigned short* qrow = Qb + ((size_t)bh * S_DIM + q0 + tq * 16 + l15) * D_DIM;
  const s16x8 qf0 = *(const s16x8*)(qrow + quad * 8);
  const s16x8 qf1 = *(const s16x8*)(qrow + 32 + quad * 8);

  // prologue: stage tile 0 (each wave 1 KB: lane part auto = +lane*16)
  glds16(kbase + t * 16, (char*)bufK[0] + wave * 1024);
  glds16(vbase + t * 16, (char*)bufV[0] + wave * 1024);

  f32x4 pv = {0.f, 0.f, 0.f, 0.f};
  float rs[4] = {0.f, 0.f, 0.f, 0.f};
  unsigned int ereg[NKT][2];

  const int krow = tn * 16 + l15;     // QK: local k col / PV: local d col
  const int sw = (l15 & 7) * 8;       // XOR swizzle for bufK/bufV reads
  const int erow0 = tq * 16 + quad * 4;

#pragma unroll
  for (int kt = 0; kt < NKT; ++kt) {
    const int p = kt & 1;
    __syncthreads();                  // drains glds(kt); PV(kt-1) complete
    const int m = mrow[kt * KTILE];
    const unsigned short* kb = bufK[p];
    f32x4 sc = {0.f, 0.f, 0.f, 0.f};
    {
      const s16x8 b0 = *(const s16x8*)(kb + krow * 64 + ((quad * 8) ^ sw));
      sc = __builtin_amdgcn_mfma_f32_16x16x32_bf16(qf0, b0, sc, 0, 0, 0);
      const s16x8 b1 = *(const s16x8*)(kb + krow * 64 + ((32 + quad * 8) ^ sw));
      sc = __builtin_amdgcn_mfma_f32_16x16x32_bf16(qf1, b1, sc, 0, 0, 0);
    }
    unsigned short e[4];
#pragma unroll
    for (int r = 0; r < 4; ++r) {
      const float ev = m ? 0.f : __expf(sc[r]);
      e[r] = f2bf(ev);
      rs[r] += bf2f(e[r]);
      et[(erow0 + r) * ETS + tn * 16 + l15] = e[r];
    }
    ereg[kt][0] = (unsigned int)e[0] | ((unsigned int)e[1] << 16);
    ereg[kt][1] = (unsigned int)e[2] | ((unsigned int)e[3] << 16);
    __syncthreads();                  // et visible (no vm outstanding: cheap)
    if (kt + 1 < NKT) {               // prefetch next tile; drained at next top sync with PV as cover
      glds16(kbase + (size_t)(kt + 1) * 8192 + t * 16, (char*)bufK[1 - p] + wave * 1024);
      glds16(vbase + (size_t)(kt + 1) * 8192 + t * 16, (char*)bufV[1 - p] + wave * 1024);
    }
    const unsigned short* vb = bufV[p];
    {
      const s16x8 a0 = *(const s16x8*)(et + (tq * 16 + l15) * ETS + quad * 8);
      const s16x8 b0 = *(const s16x8*)(vb + krow * 64 + ((quad * 8) ^ sw));
      pv = __builtin_amdgcn_mfma_f32_16x16x32_bf16(a0, b0, pv, 0, 0, 0);
      const s16x8 a1 = *(const s16x8*)(et + (tq * 16 + l15) * ETS + 32 + quad * 8);
      const s16x8 b1 = *(const s16x8*)(vb + krow * 64 + ((32 + quad * 8) ^ sw));
      pv = __builtin_amdgcn_mfma_f32_16x16x32_bf16(a1, b1, pv, 0, 0, 0);
    }
  }

  // row-sum reduction: 16 lanes sharing quad hold same rows
#pragma unroll
  for (int o = 1; o < 16; o <<= 1) {
#pragma unroll
    for (int r = 0; r < 4; ++r) rs[r] += __shfl_xor(rs[r], o);
  }
  if (l15 == 0) {
#pragma unroll
    for (int r = 0; r < 4; ++r) sums_part[wave * 16 + quad * 4 + r] = rs[r];
  }
  __syncthreads();
  if (t < QT) {
    const int tqi = t >> 4, rl = t & 15;
    float s = 0.f;
#pragma unroll
    for (int w = 0; w < 4; ++w) s += sums_part[(tqi * 4 + w) * 16 + rl];
    inv_sums[t] = 1.f / fmaxf(s, 1e-30f);
  }
  __syncthreads();

  float inv_r[4];
#pragma unroll
  for (int r = 0; r < 4; ++r) inv_r[r] = inv_sums[erow0 + r];

  // sum_value
  {
    float* svo = Out + ATTN_ELEMS + ((size_t)bh * S_DIM + q0) * D_DIM;
#pragma unroll
    for (int r = 0; r < 4; ++r)
      svo[(size_t)(erow0 + r) * D_DIM + tn * 16 + l15] = pv[r] * inv_r[r];
  }

  // attention: regs -> LDS stage (double-buffered) -> coalesced float4 stores
  float* ao = Out + (size_t)bh * S_DIM * S_DIM + (size_t)q0 * S_DIM;
  const int row_t = t >> 4;
  const int c4 = t & 15;
#pragma unroll
  for (int kt = 0; kt < NKT; ++kt) {
    float* sg = stage[kt & 1];
    sg[(erow0 + 0) * STS + tn * 16 + l15] = bf2f((unsigned short)(ereg[kt][0] & 0xFFFFu)) * inv_r[0];
    sg[(erow0 + 1) * STS + tn * 16 + l15] = bf2f((unsigned short)(ereg[kt][0] >> 16)) * inv_r[1];
    sg[(erow0 + 2) * STS + tn * 16 + l15] = bf2f((unsigned short)(ereg[kt][1] & 0xFFFFu)) * inv_r[2];
    sg[(erow0 + 3) * STS + tn * 16 + l15] = bf2f((unsigned short)(ereg[kt][1] >> 16)) * inv_r[3];
    __syncthreads();
    const float4 o = *(const float4*)(sg + row_t * STS + c4 * 4);
    *(float4*)(ao + (size_t)row_t * S_DIM + kt * KTILE + c4 * 4) = o;
  }
}

extern "C" void kernel_launch(void* const* d_in, const int* in_sizes, int n_in,
                              void* d_out, int out_size, void* d_ws, size_t ws_size,
                              hipStream_t stream) {
  const float* Q = (const float*)d_in[0];
  const float* K = (const float*)d_in[1];
  const float* V = (const float*)d_in[2];
  const int* M = (const int*)d_in[3];
  float* out = (float*)d_out;
  unsigned short* Qb = (unsigned short*)d_ws;          // needs 24 MB of ws
  unsigned short* Kb = Qb + QELEMS;
  unsigned short* Vtb = Kb + QELEMS;
  hipLaunchKernelGGL(prep_kernel, dim3(3072), dim3(256), 0, stream, Q, K, V, Qb, Kb, Vtb);
  hipLaunchKernelGGL(attn_kernel, dim3(2048), dim3(NT), 0, stream, M, Qb, Kb, Vtb, out);
}